// Round 6
// baseline (583.312 us; speedup 1.0000x reference)
//
#include <hip/hip_runtime.h>
#include <stdint.h>

// Shapes (fixed by reference): B=32, S=2048, D=1024.
#define BDIM 32
#define SDIM 2048
#define DDIM 1024
#define MDIM (BDIM * SDIM)   // 65536 rows of the GEMM
#define K_STEPS 16           // 1024 / BK, BK=64

typedef __bf16 bf16x8 __attribute__((ext_vector_type(8)));
typedef float  f32x4  __attribute__((ext_vector_type(4)));

// ---------- helpers ----------

__device__ inline unsigned short f2bf(float f) {
  union { float f; unsigned u; } un; un.f = f;
  unsigned r = un.u + 0x7fffu + ((un.u >> 16) & 1u);   // RNE
  return (unsigned short)(r >> 16);
}

__device__ inline float fast_tanh(float x) {
  float e = __expf(2.0f * x);
  return 1.0f - 2.0f / (e + 1.0f);
}

__device__ inline void gl_lds16(const unsigned short* g, unsigned short* l) {
  __builtin_amdgcn_global_load_lds(
      (__attribute__((address_space(1))) unsigned int*)(void*)(uintptr_t)g,
      (__attribute__((address_space(3))) unsigned int*)l,
      16, 0, 0);
}

// ---------- kernel 1: fp32 -> bf16 convert (W only, 8 elems/thread) ----------

__global__ __launch_bounds__(256) void cvt_kernel(const float* __restrict__ src,
                                                  unsigned short* __restrict__ dst) {
  size_t i = (size_t)blockIdx.x * 256 + threadIdx.x;
  const float4* s4 = (const float4*)src;
  float4 a = s4[2 * i];
  float4 b = s4[2 * i + 1];
  uint4 o;
  o.x = (unsigned)f2bf(a.x) | ((unsigned)f2bf(a.y) << 16);
  o.y = (unsigned)f2bf(a.z) | ((unsigned)f2bf(a.w) << 16);
  o.z = (unsigned)f2bf(b.x) | ((unsigned)f2bf(b.y) << 16);
  o.w = (unsigned)f2bf(b.z) | ((unsigned)f2bf(b.w) << 16);
  ((uint4*)dst)[i] = o;
}

// ---------- kernel 2: fused cvt+GEMM, 2-phase pipelined (dbuf, raw barrier) --
// logitsP[nt*2+(w&1)][m] = sum_{n in wave's 64-col half} tanh(...) * v[n]
// Pipeline per K-step (ONE raw s_barrier, counted waits -- T3min/T4/T14/T5):
//   top:    issue W global_load_lds(kt+1) -> Wl[nxt]          (async)
//   mid:    ds_read frags from buf[cur]; setprio(1); 32 MFMA; setprio(0)
//   stage:  vmcnt(0)  [A regs(kt+1) + W lds(kt+1) landed]
//           cvt+ds_write A(kt+1) -> Al[nxt]; issue A loads(kt+2) -> regs
//   close:  lgkmcnt(0); s_barrier
// A-load latency hides under previous step's MFMA (regs in flight across the
// barrier); W gl_lds latency hides under this step's MFMA.  __syncthreads is
// NOT used in the loop (its vmcnt(0) drain would kill the prefetch).
// Swizzle, fragment reads, epilogue identical to round-5 (refcheck-verified).

__global__ __launch_bounds__(256) void gemm_logits(
    const float* __restrict__ ctx,          // [M][1024] fp32
    const unsigned short* __restrict__ Bw,  // [1024][1024] bf16 W
    const float* __restrict__ v,
    float* __restrict__ logitsP)            // [16][M] partial planes
{
  __shared__ __align__(16) unsigned short Al[2][128 * 64];  // 32 KB
  __shared__ __align__(16) unsigned short Wl[2][128 * 64];  // 32 KB

  const int t  = threadIdx.x;
  const int l  = (blockIdx.x & 7) * 512 + (blockIdx.x >> 3);
  const int mt = l >> 3;
  const int nt = l & 7;
  const int m0 = mt * 128;
  const int n0 = nt * 128;
  const int w    = t >> 6;
  const int lane = t & 63;
  const int c = lane & 15;        // frag col/row within 16
  const int q = lane >> 4;        // frag quad
  const int wm = (w >> 1) * 64;   // wave row offset in tile
  const int wn = (w & 1) * 64;    // wave col offset in tile

  float vv[4];
#pragma unroll
  for (int ni = 0; ni < 4; ++ni) vv[ni] = v[n0 + wn + ni * 16 + c];

  f32x4 acc[4][4] = {};

  // staging geometry: 128 rows x 8 chunks of 16B(bf16) per tile
  const int rt  = t >> 3;          // 0..31 row part
  const int sA  = t & 7;           // chunk index
  const int psl = sA ^ (rt & 7);   // swizzled slot (== pre-swizzled src chunk)
  const float* gA = ctx + (size_t)(m0 + rt) * DDIM + sA * 8;   // fp32, linear
  const unsigned short* gb = Bw + (size_t)(n0 + rt) * DDIM + psl * 8;
  const int lwoff = (t & 192) * 8;   // wave-uniform LDS element offset

  float4 pa[4][2];   // A prefetch registers (one K-step ahead)

  auto A_LOAD = [&](int kt) {
#pragma unroll
    for (int j = 0; j < 4; ++j) {
      const float* g = gA + (size_t)(j * 32) * DDIM + kt * 64;
      pa[j][0] = *(const float4*)g;
      pa[j][1] = *(const float4*)(g + 4);
    }
  };
  auto A_WRITE = [&](int buf) {
#pragma unroll
    for (int j = 0; j < 4; ++j) {
      const int row = j * 32 + rt;
      bf16x8 cv;
      cv[0] = (__bf16)pa[j][0].x; cv[1] = (__bf16)pa[j][0].y;
      cv[2] = (__bf16)pa[j][0].z; cv[3] = (__bf16)pa[j][0].w;
      cv[4] = (__bf16)pa[j][1].x; cv[5] = (__bf16)pa[j][1].y;
      cv[6] = (__bf16)pa[j][1].z; cv[7] = (__bf16)pa[j][1].w;
      *(bf16x8*)&Al[buf][row * 64 + psl * 8] = cv;
    }
  };
  auto W_ISSUE = [&](int kt, int buf) {
#pragma unroll
    for (int r = 0; r < 4; ++r)
      gl_lds16(gb + (size_t)(r * 32) * DDIM + kt * 64,
               &Wl[buf][r * 2048 + lwoff]);
  };

  // ---- prologue: fill buffer 0, prefetch A(1) ----
  A_LOAD(0);
  W_ISSUE(0, 0);
  asm volatile("s_waitcnt vmcnt(0)" ::: "memory");
  A_WRITE(0);
  A_LOAD(1);
  asm volatile("s_waitcnt lgkmcnt(0)" ::: "memory");
  __builtin_amdgcn_s_barrier();

  // ---- main loop: one barrier per K-step ----
#pragma unroll 2
  for (int kt = 0; kt < K_STEPS; ++kt) {
    const int cur = kt & 1;
    const int nxt = cur ^ 1;
    if (kt + 1 < K_STEPS) W_ISSUE(kt + 1, nxt);

    __builtin_amdgcn_s_setprio(1);
#pragma unroll
    for (int kk = 0; kk < 2; ++kk) {
      bf16x8 af[4], bfr[4];
      const int slot = ((kk * 4 + q) ^ (c & 7)) * 8;
#pragma unroll
      for (int mi = 0; mi < 4; ++mi)
        af[mi] = *(const bf16x8*)&Al[cur][(wm + mi * 16 + c) * 64 + slot];
#pragma unroll
      for (int ni = 0; ni < 4; ++ni)
        bfr[ni] = *(const bf16x8*)&Wl[cur][(wn + ni * 16 + c) * 64 + slot];
#pragma unroll
      for (int mi = 0; mi < 4; ++mi)
#pragma unroll
        for (int ni = 0; ni < 4; ++ni)
          acc[mi][ni] = __builtin_amdgcn_mfma_f32_16x16x32_bf16(
              af[mi], bfr[ni], acc[mi][ni], 0, 0, 0);
    }
    __builtin_amdgcn_s_setprio(0);

    if (kt + 1 < K_STEPS) {
      // A regs(kt+1) and W gl_lds(kt+1) both landed after this:
      asm volatile("s_waitcnt vmcnt(0)" ::: "memory");
      A_WRITE(nxt);
      if (kt + 2 < K_STEPS) A_LOAD(kt + 2);
    }
    asm volatile("s_waitcnt lgkmcnt(0)" ::: "memory");
    __builtin_amdgcn_s_barrier();
  }

  // Epilogue: tanh, dot with v over this wave's 64 columns, shfl-reduce over
  // the 16 c-lanes, store to this wave's own plane (no atomics, no overlap).
  // C/D layout (16x16): col = lane&15, row = (lane>>4)*4 + reg.
  const size_t plane = (size_t)(nt * 2 + (w & 1)) * MDIM;
#pragma unroll
  for (int mi = 0; mi < 4; ++mi) {
    float p0 = 0.f, p1 = 0.f, p2 = 0.f, p3 = 0.f;
#pragma unroll
    for (int ni = 0; ni < 4; ++ni) {
      const float vvn = vv[ni];
      p0 += fast_tanh(acc[mi][ni][0]) * vvn;
      p1 += fast_tanh(acc[mi][ni][1]) * vvn;
      p2 += fast_tanh(acc[mi][ni][2]) * vvn;
      p3 += fast_tanh(acc[mi][ni][3]) * vvn;
    }
#pragma unroll
    for (int mask = 1; mask <= 8; mask <<= 1) {
      p0 += __shfl_xor(p0, mask);
      p1 += __shfl_xor(p1, mask);
      p2 += __shfl_xor(p2, mask);
      p3 += __shfl_xor(p3, mask);
    }
    if (c == 0) {
      float4 o = {p0, p1, p2, p3};
      *(float4*)(logitsP + plane + m0 + wm + mi * 16 + q * 4) = o;
    }
  }
}

// ---------- kernel 3: plane-sum (16 planes) + per-batch softmax ----------

__global__ __launch_bounds__(256) void softmax_kernel(const float* __restrict__ P,
                                                      float* __restrict__ attn) {
  const int b = blockIdx.x;
  const int t = threadIdx.x;
  float x[8];
#pragma unroll
  for (int i = 0; i < 8; ++i) {
    const size_t off = (size_t)b * SDIM + i * 256 + t;
    float s = 0.f;
#pragma unroll
    for (int pl = 0; pl < 16; ++pl) s += P[(size_t)pl * MDIM + off];
    x[i] = s;
  }
  float m = x[0];
#pragma unroll
  for (int i = 1; i < 8; ++i) m = fmaxf(m, x[i]);
#pragma unroll
  for (int mask = 1; mask < 64; mask <<= 1) m = fmaxf(m, __shfl_xor(m, mask));
  __shared__ float redm[4], reds[4];
  const int w = t >> 6, lane = t & 63;
  if (lane == 0) redm[w] = m;
  __syncthreads();
  m = fmaxf(fmaxf(redm[0], redm[1]), fmaxf(redm[2], redm[3]));
  float e[8];
  float s = 0.f;
#pragma unroll
  for (int i = 0; i < 8; ++i) { e[i] = __expf(x[i] - m); s += e[i]; }
#pragma unroll
  for (int mask = 1; mask < 64; mask <<= 1) s += __shfl_xor(s, mask);
  if (lane == 0) reds[w] = s;
  __syncthreads();
  s = reds[0] + reds[1] + reds[2] + reds[3];
  const float inv = 1.0f / s;
  float* p = attn + (size_t)b * SDIM;
#pragma unroll
  for (int i = 0; i < 8; ++i) p[i * 256 + t] = e[i] * inv;
}

// ---------- kernel 4: weighted context partial sums (no atomics) ----------
// part[b][sc][d] = sum_{s in 32-row chunk sc} attn[b][s] * ctx[b][s][d]

__global__ __launch_bounds__(256) void wsum_part(const float* __restrict__ ctx,
                                                 const float* __restrict__ attn,
                                                 float* __restrict__ part) {
  const int b  = blockIdx.x >> 6;
  const int sc = blockIdx.x & 63;
  const int t  = threadIdx.x;
  const float* cp = ctx + ((size_t)b * SDIM + sc * 32) * DDIM + t * 4;
  const float* ap = attn + (size_t)b * SDIM + sc * 32;
  float4 acc = {0.f, 0.f, 0.f, 0.f};
#pragma unroll 4
  for (int s = 0; s < 32; ++s) {
    const float a = ap[s];
    const float4 cv = *(const float4*)(cp + (size_t)s * DDIM);
    acc.x += a * cv.x; acc.y += a * cv.y; acc.z += a * cv.z; acc.w += a * cv.w;
  }
  *(float4*)(part + (size_t)blockIdx.x * DDIM + t * 4) = acc;
}

// ---------- kernel 5: reduce the 64 partials per (b, d) ----------

__global__ __launch_bounds__(256) void wsum_reduce(const float* __restrict__ part,
                                                   float* __restrict__ wc) {
  const int b = blockIdx.x >> 2;
  const int d = (blockIdx.x & 3) * 256 + threadIdx.x;
  float s = 0.f;
#pragma unroll
  for (int sc = 0; sc < 64; ++sc)
    s += part[((size_t)b * 64 + sc) * DDIM + d];
  wc[(size_t)b * DDIM + d] = s;
}

// ---------- launch ----------

extern "C" void kernel_launch(void* const* d_in, const int* in_sizes, int n_in,
                              void* d_out, int out_size, void* d_ws, size_t ws_size,
                              hipStream_t stream) {
  const float* ctx = (const float*)d_in[0];   // [32,2048,1024] fp32
  const float* W   = (const float*)d_in[1];   // [1024,1024] fp32
  const float* v   = (const float*)d_in[2];   // [1024] fp32
  // d_in[3] = scalar b: softmax-invariant, unused.

  float* out_wc   = (float*)d_out;            // [32,1024]
  float* out_attn = out_wc + BDIM * DDIM;     // [32,2048]

  float* logitsP = (float*)d_ws;                         // [16][M] = 4 MB
  float* part    = logitsP + (size_t)16 * MDIM;          // [2048][1024] = 8 MB
  unsigned short* W_bf = (unsigned short*)(part + (size_t)2048 * DDIM);  // 2 MB

  cvt_kernel<<<(DDIM * DDIM) / (256 * 8), 256, 0, stream>>>(W, W_bf);
  gemm_logits<<<(MDIM / 128) * (DDIM / 128), 256, 0, stream>>>(ctx, W_bf, v, logitsP);
  softmax_kernel<<<BDIM, 256, 0, stream>>>(logitsP, out_attn);
  wsum_part<<<BDIM * 64, 256, 0, stream>>>(ctx, out_attn, part);
  wsum_reduce<<<(BDIM * DDIM) / 256, 256, 0, stream>>>(part, out_wc);
}